// Round 3
// baseline (255.294 us; speedup 1.0000x reference)
//
#include <hip/hip_runtime.h>
#include <cstdint>

// ---------------------------------------------------------------------------
// GRUCell w/ BatchNorm on input projection.  B=4096, I=H=1024, 3H=3072.
// NOTE reference semantics:  c = tanh(c_bn + (r * hx) @ c_h)   («*» and «@»
// are same-precedence left-assoc in Python!) -> needs a 3rd dependent GEMM.
//   g   = input @ wi                       (split-bf16 MFMA)
//   BN column stats -> folded scale/shift
//   gh  = hx @ wh[:, :2H]                  (split-bf16 MFMA)
//   r   = sigmoid(BN(g_r) + gh_r);  rx = r * hx   (bf16 hi/lo)
//   ch  = rx @ wh[:, 2H:]                  (split-bf16 MFMA, into ghbuf r-cols)
//   hy  = (1-u)*hx + u*tanh(BN(g_c) + ch)
// ---------------------------------------------------------------------------

typedef unsigned short u16;
typedef float   f4     __attribute__((ext_vector_type(4)));
typedef u16     u16x4  __attribute__((ext_vector_type(4)));
typedef u16     u16x8  __attribute__((ext_vector_type(8)));
typedef short   bf16x8 __attribute__((ext_vector_type(8)));
typedef float   f32x4  __attribute__((ext_vector_type(4)));

__device__ __forceinline__ u16 f2bf(float f) {
  union { float f; unsigned u; } v; v.f = f;
  unsigned r = v.u + 0x7FFFu + ((v.u >> 16) & 1u);   // RNE
  return (u16)(r >> 16);
}
__device__ __forceinline__ float bf2f(u16 h) {
  union { unsigned u; float f; } v; v.u = ((unsigned)h) << 16;
  return v.f;
}

// --------------------------- prep kernels ----------------------------------

__global__ void convert_hl(const float* __restrict__ src, u16* __restrict__ hi,
                           u16* __restrict__ lo, int n4) {
  int i = blockIdx.x * blockDim.x + threadIdx.x;
  if (i >= n4) return;
  f4 v = ((const f4*)src)[i];
  u16x4 h, l;
#pragma unroll
  for (int j = 0; j < 4; ++j) {
    u16 hh = f2bf(v[j]);
    h[j] = hh;
    l[j] = f2bf(v[j] - bf2f(hh));
  }
  ((u16x4*)hi)[i] = h;
  ((u16x4*)lo)[i] = l;
}

// W [K][N] f32  ->  Wt [N][K] bf16 hi + lo
__global__ void transpose_hl(const float* __restrict__ W, u16* __restrict__ Th,
                             u16* __restrict__ Tl, int K, int N) {
  __shared__ float sh[32][33];
  int n0 = blockIdx.x * 32, k0 = blockIdx.y * 32;
  int tx = threadIdx.x & 31, ty = threadIdx.x >> 5;  // ty 0..7
#pragma unroll
  for (int i = 0; i < 4; ++i) {
    int k = ty + i * 8;
    sh[k][tx] = W[(size_t)(k0 + k) * N + n0 + tx];
  }
  __syncthreads();
#pragma unroll
  for (int i = 0; i < 4; ++i) {
    int nn = ty + i * 8;
    float v = sh[tx][nn];                      // = W[k0+tx][n0+nn]
    size_t o = (size_t)(n0 + nn) * K + k0 + tx;
    u16 h = f2bf(v);
    Th[o] = h;
    Tl[o] = f2bf(v - bf2f(h));
  }
}

// ------------------------------- GEMM ---------------------------------------
// C[.][ldC] f32 (Ncols written) = A[M][K] @ B[K][Ncols]; A row-major bf16
// hi/lo, B pre-transposed Bt[Ncols][K] bf16 hi/lo.  128x128 tile, BK=64,
// 4 waves (2x2), 4x4 frags of mfma_f32_16x16x32_bf16, 3 passes
// (Ah*Bh + Ah*Bl + Al*Bh).  LDS [128 rows][8 slots of 8 u16],
// slot stored at slot ^ (row&7) (same fn on write & read).

#define BM 128
#define BN 128
#define BK 64

__global__ __launch_bounds__(256, 2) void gemm_split(
    const u16* __restrict__ Ah, const u16* __restrict__ Al,
    const u16* __restrict__ Bh, const u16* __restrict__ Bl,
    float* __restrict__ C, int ldC, int K) {
  constexpr int TE = BM * BK;                 // 8192 u16 = 16 KiB
  __shared__ u16 lds[4 * TE];                 // Ah | Bh | Al | Bl

  const int tid  = threadIdx.x;
  const int lane = tid & 63;
  const int wid  = tid >> 6;
  const int brow = blockIdx.y * BM;
  const int bcol = blockIdx.x * BN;
  const int wrow = (wid >> 1) * 64;
  const int wcol = (wid & 1) * 64;

  f32x4 acc[4][4];
#pragma unroll
  for (int i = 0; i < 4; ++i)
#pragma unroll
    for (int j = 0; j < 4; ++j) acc[i][j] = f32x4{0.f, 0.f, 0.f, 0.f};

  const int NT = K / BK;
  for (int kt = 0; kt < NT; ++kt) {
    const int k0 = kt * BK;

    // ---- global -> registers (overlaps prev compute)
    u16x8 rA[4], rB[4], rAl[4], rBl[4];
#pragma unroll
    for (int i = 0; i < 4; ++i) {
      int c = i * 256 + tid;                  // 0..1023 16B-chunks per tile
      int row = c >> 3, slot = c & 7;
      size_t ga = (size_t)(brow + row) * K + k0 + slot * 8;
      size_t gb = (size_t)(bcol + row) * K + k0 + slot * 8;
      rA[i]  = *(const u16x8*)(Ah + ga);
      rB[i]  = *(const u16x8*)(Bh + gb);
      rAl[i] = *(const u16x8*)(Al + ga);
      rBl[i] = *(const u16x8*)(Bl + gb);
    }

    __syncthreads();                          // prev tile's LDS reads done

    // ---- registers -> LDS (XOR-swizzled slots)
#pragma unroll
    for (int i = 0; i < 4; ++i) {
      int c = i * 256 + tid;
      int row = c >> 3, slot = c & 7;
      int off = row * 64 + (slot ^ (row & 7)) * 8;
      *(u16x8*)(lds + off)          = rA[i];
      *(u16x8*)(lds + TE + off)     = rB[i];
      *(u16x8*)(lds + 2 * TE + off) = rAl[i];
      *(u16x8*)(lds + 3 * TE + off) = rBl[i];
    }
    __syncthreads();                          // staged data visible

    // ---- compute: two K=32 halves
#pragma unroll
    for (int h = 0; h < 2; ++h) {
      bf16x8 a_h[4], b_h[4], a_l[4], b_l[4];
      const int kg = h * 4 + (lane >> 4);     // 16B k-group 0..7
#pragma unroll
      for (int m = 0; m < 4; ++m) {
        int r = wrow + m * 16 + (lane & 15);
        int off = r * 64 + (kg ^ (r & 7)) * 8;
        a_h[m] = *(const bf16x8*)(lds + off);
        a_l[m] = *(const bf16x8*)(lds + 2 * TE + off);
      }
#pragma unroll
      for (int n = 0; n < 4; ++n) {
        int r = wcol + n * 16 + (lane & 15);
        int off = r * 64 + (kg ^ (r & 7)) * 8;
        b_h[n] = *(const bf16x8*)(lds + TE + off);
        b_l[n] = *(const bf16x8*)(lds + 3 * TE + off);
      }
#pragma unroll
      for (int m = 0; m < 4; ++m)
#pragma unroll
        for (int n = 0; n < 4; ++n) {
          acc[m][n] = __builtin_amdgcn_mfma_f32_16x16x32_bf16(
              a_h[m], b_h[n], acc[m][n], 0, 0, 0);
          acc[m][n] = __builtin_amdgcn_mfma_f32_16x16x32_bf16(
              a_h[m], b_l[n], acc[m][n], 0, 0, 0);
          acc[m][n] = __builtin_amdgcn_mfma_f32_16x16x32_bf16(
              a_l[m], b_h[n], acc[m][n], 0, 0, 0);
        }
    }
  }

  // epilogue: D(row,col): col = lane&15, row = (lane>>4)*4 + j
#pragma unroll
  for (int m = 0; m < 4; ++m) {
    int row = brow + wrow + m * 16 + (lane >> 4) * 4;
#pragma unroll
    for (int n = 0; n < 4; ++n) {
      int col = bcol + wcol + n * 16 + (lane & 15);
      float* cp = C + (size_t)row * ldC + col;
#pragma unroll
      for (int j = 0; j < 4; ++j) cp[(size_t)j * ldC] = acc[m][n][j];
    }
  }
}

// --------------------------- BN stats ---------------------------------------

__global__ void bn_partial(const float* __restrict__ g, float* __restrict__ psum,
                           float* __restrict__ psq, int rows_per, int Ncols) {
  int col = blockIdx.x * blockDim.x + threadIdx.x;
  int rb  = blockIdx.y;
  const float* p = g + (size_t)rb * rows_per * Ncols + col;
  float s = 0.f, q = 0.f;
  for (int i = 0; i < rows_per; ++i) {
    float v = p[(size_t)i * Ncols];
    s += v; q += v * v;
  }
  psum[(size_t)rb * Ncols + col] = s;
  psq [(size_t)rb * Ncols + col] = q;
}

__global__ void bn_final(const float* __restrict__ psum, const float* __restrict__ psq,
                         const float* __restrict__ gamma, const float* __restrict__ beta,
                         const float* __restrict__ bias, float* __restrict__ scale,
                         float* __restrict__ shift, int nparts, int Ncols, float invM) {
  int col = blockIdx.x * blockDim.x + threadIdx.x;
  if (col >= Ncols) return;
  float s = 0.f, q = 0.f;
  for (int i = 0; i < nparts; ++i) {
    s += psum[(size_t)i * Ncols + col];
    q += psq [(size_t)i * Ncols + col];
  }
  float m   = s * invM;
  float var = q * invM - m * m;
  float r   = rsqrtf(var + 1e-5f);
  float sc  = r * gamma[col];
  scale[col] = sc;
  shift[col] = beta[col] + bias[col] - m * sc;
}

// --------------------- r-gate + rx = r*hx (bf16 split) ----------------------

__global__ void rx_split(const float* __restrict__ g, const float* __restrict__ gh,
                         const float* __restrict__ hx, const float* __restrict__ scale,
                         const float* __restrict__ shift, u16* __restrict__ rxh,
                         u16* __restrict__ rxl) {
  int idx = blockIdx.x * blockDim.x + threadIdx.x;  // 4096*256
  int row = idx >> 8;
  int cv  = idx & 255;
  f4 gr = ((const f4*)g )[(size_t)row * 768 + 256 + cv];   // g cols 1024..2047
  f4 hr = ((const f4*)gh)[(size_t)row * 512 + 256 + cv];   // gh cols 1024..2047
  f4 xv = ((const f4*)hx)[(size_t)row * 256 + cv];
  int col = 1024 + cv * 4;
  f4 sr = *(const f4*)&scale[col];
  f4 fr = *(const f4*)&shift[col];
  u16x4 h, l;
#pragma unroll
  for (int j = 0; j < 4; ++j) {
    float r = 1.f / (1.f + __expf(-(gr[j] * sr[j] + fr[j] + hr[j])));
    float v = r * xv[j];
    u16 hh = f2bf(v);
    h[j] = hh;
    l[j] = f2bf(v - bf2f(hh));
  }
  ((u16x4*)rxh)[(size_t)row * 256 + cv] = h;
  ((u16x4*)rxl)[(size_t)row * 256 + cv] = l;
}

// --------------------------- fused gates ------------------------------------
// gh layout now: cols 0..1023 = hu,  cols 1024..2047 = ch (GEMM3 output)

__global__ void fuse_out(const float* __restrict__ g, const float* __restrict__ gh,
                         const float* __restrict__ hx, const float* __restrict__ scale,
                         const float* __restrict__ shift, float* __restrict__ out) {
  int idx = blockIdx.x * blockDim.x + threadIdx.x;  // 4096*256
  int row = idx >> 8;
  int cv  = idx & 255;
  f4 gu = ((const f4*)g )[(size_t)row * 768 + cv];         // g cols 0..1023
  f4 gc = ((const f4*)g )[(size_t)row * 768 + 512 + cv];   // g cols 2048..3071
  f4 hu = ((const f4*)gh)[(size_t)row * 512 + cv];         // gh cols 0..1023
  f4 ch = ((const f4*)gh)[(size_t)row * 512 + 256 + cv];   // ch
  f4 xv = ((const f4*)hx)[(size_t)row * 256 + cv];
  int col = cv * 4;
  f4 su = *(const f4*)&scale[col];
  f4 fu = *(const f4*)&shift[col];
  f4 sc = *(const f4*)&scale[col + 2048];
  f4 fc = *(const f4*)&shift[col + 2048];
  f4 res;
#pragma unroll
  for (int j = 0; j < 4; ++j) {
    float u = 1.f / (1.f + __expf(-(gu[j] * su[j] + fu[j] + hu[j])));
    float t = gc[j] * sc[j] + fc[j] + ch[j];
    float c = 1.f - 2.f / (__expf(2.f * t) + 1.f);  // tanh, saturates correctly
    res[j] = xv[j] + u * (c - xv[j]);
  }
  ((f4*)out)[(size_t)row * 256 + cv] = res;
}

// ------------------------------ launch ---------------------------------------

extern "C" void kernel_launch(void* const* d_in, const int* in_sizes, int n_in,
                              void* d_out, int out_size, void* d_ws, size_t ws_size,
                              hipStream_t stream) {
  const float* input = (const float*)d_in[0];   // 4096x1024
  const float* hx    = (const float*)d_in[1];   // 4096x1024
  const float* wi    = (const float*)d_in[2];   // 1024x3072
  const float* wh    = (const float*)d_in[3];   // 1024x3072
  const float* bias  = (const float*)d_in[4];   // 3072
  const float* gamma = (const float*)d_in[5];   // 3072
  const float* beta  = (const float*)d_in[6];   // 3072
  float* out = (float*)d_out;

  const int B = 4096, I = 1024, H = 1024, N3 = 3072;

  char* ws = (char*)d_ws;
  float* gbuf  = (float*)(ws);                      // 48 MiB   [4096][3072]
  float* ghbuf = (float*)(ws + 50331648);           // 32 MiB   [4096][2048]
  u16*   Xh    = (u16*)(ws + 83886080);             // 8 MiB  (input -> hx -> rx)
  u16*   Xl    = (u16*)(ws + 92274688);             // 8 MiB
  u16*   WiTh  = (u16*)(ws + 100663296);            // 6 MiB   wi^T hi
  u16*   WiTl  = (u16*)(ws + 106954752);            // 6 MiB   wi^T lo
  u16*   WhTh  = (u16*)(ws + 113246208);            // 6 MiB   wh^T hi
  u16*   WhTl  = (u16*)(ws + 119537664);            // 6 MiB   wh^T lo
  float* psum  = (float*)(ws + 125829120);          // 384 KiB
  float* psq   = (float*)(ws + 126222336);          // 384 KiB
  float* scale = (float*)(ws + 126615552);          // 12 KiB
  float* shift = (float*)(ws + 126627840);          // 12 KiB

  // ---- prep
  convert_hl<<<1024 * 4, 256, 0, stream>>>(input, Xh, Xl, B * I / 4);
  transpose_hl<<<dim3(96, 32), 256, 0, stream>>>(wi, WiTh, WiTl, I, N3);
  transpose_hl<<<dim3(96, 32), 256, 0, stream>>>(wh, WhTh, WhTl, H, N3);

  // ---- GEMM1: g = input @ wi   (full 3072 cols)
  gemm_split<<<dim3(N3 / BN, B / BM), 256, 0, stream>>>(
      Xh, Xl, WiTh, WiTl, gbuf, N3, I);

  // ---- BN stats -> folded scale/shift
  bn_partial<<<dim3(N3 / 256, 32), 256, 0, stream>>>(gbuf, psum, psq, B / 32, N3);
  bn_final<<<N3 / 256, 256, 0, stream>>>(psum, psq, gamma, beta, bias,
                                         scale, shift, 32, N3, 1.f / (float)B);

  // ---- GEMM2: gh = hx @ wh[:, :2048]   (u and r parts)
  convert_hl<<<1024 * 4, 256, 0, stream>>>(hx, Xh, Xl, B * H / 4);
  gemm_split<<<dim3(2048 / BN, B / BM), 256, 0, stream>>>(
      Xh, Xl, WhTh, WhTl, ghbuf, 2048, H);

  // ---- rx = sigmoid(BN(g_r) + gh_r) * hx   (bf16 split; overwrites Xh/Xl)
  rx_split<<<1024 * 4, 256, 0, stream>>>(gbuf, ghbuf, hx, scale, shift, Xh, Xl);

  // ---- GEMM3: ch = rx @ wh[:, 2048:]  -> ghbuf cols 1024..2047 (r-cols dead)
  gemm_split<<<dim3(1024 / BN, B / BM), 256, 0, stream>>>(
      Xh, Xl, WhTh + (size_t)2048 * 1024, WhTl + (size_t)2048 * 1024,
      ghbuf + 1024, 2048, H);

  // ---- fused gate epilogue
  fuse_out<<<1024 * 4, 256, 0, stream>>>(gbuf, ghbuf, hx, scale, shift, out);
}

// Round 4
// 176.620 us; speedup vs baseline: 1.4454x; 1.4454x over previous
//
#include <hip/hip_runtime.h>
#include <cstdint>

// ---------------------------------------------------------------------------
// GRUCell w/ BatchNorm on input projection.  B=4096, I=H=1024, 3H=3072.
// Reference:  c = tanh(c_bn + (r * hx) @ c_h)  (Python left-assoc * then @).
// fp16 precision scheme (all MFMA = mfma_f32_16x16x32_f16, fp32 accum):
//   GEMM1: g  = input @ wi          1-pass fp16 (BN divides error by sigma~32)
//   GEMM2: gh = hx @ wh[:, :2H]     2-pass (A fp16 once; B split hi+lo fp16)
//   GEMM3: ch = rx @ wh[:, 2H:]     2-pass
// Fused epilogues: GEMM1 -> BN column partials; GEMM2 -> u (fp16) + rx (fp16);
// GEMM3 -> full gate math -> hy.
// ---------------------------------------------------------------------------

typedef float    f4    __attribute__((ext_vector_type(4)));
typedef _Float16 half4 __attribute__((ext_vector_type(4)));
typedef _Float16 half8 __attribute__((ext_vector_type(8)));
typedef float    f32x4 __attribute__((ext_vector_type(4)));

__device__ __forceinline__ float sigm(float x) {
  return 1.f / (1.f + __expf(-x));
}
__device__ __forceinline__ float tanh_sat(float t) {
  return 1.f - 2.f / (__expf(2.f * t) + 1.f);   // saturates correctly for big t
}

// --------------------------- prep kernels ----------------------------------

// f32 -> fp16, vectorized x4
__global__ void convert16(const float* __restrict__ src,
                          _Float16* __restrict__ dst, int n4) {
  int i = blockIdx.x * blockDim.x + threadIdx.x;
  if (i >= n4) return;
  f4 v = ((const f4*)src)[i];
  half4 h;
#pragma unroll
  for (int j = 0; j < 4; ++j) h[j] = (_Float16)v[j];
  ((half4*)dst)[i] = h;
}

// W [K][N] f32 -> Wt [N][K] fp16 hi (+ optional lo)
__global__ void transpose16(const float* __restrict__ W,
                            _Float16* __restrict__ Th, _Float16* __restrict__ Tl,
                            int K, int N) {
  __shared__ float sh[32][33];
  int n0 = blockIdx.x * 32, k0 = blockIdx.y * 32;
  int tx = threadIdx.x & 31, ty = threadIdx.x >> 5;  // ty 0..7
#pragma unroll
  for (int i = 0; i < 4; ++i) {
    int k = ty + i * 8;
    sh[k][tx] = W[(size_t)(k0 + k) * N + n0 + tx];
  }
  __syncthreads();
#pragma unroll
  for (int i = 0; i < 4; ++i) {
    int nn = ty + i * 8;
    float v = sh[tx][nn];                      // = W[k0+tx][n0+nn]
    size_t o = (size_t)(n0 + nn) * K + k0 + tx;
    _Float16 h = (_Float16)v;
    Th[o] = h;
    if (Tl) Tl[o] = (_Float16)(v - (float)h);
  }
}

// ------------------------------- GEMM ---------------------------------------
// 128x128 tile, BK=64, 4 waves (2x2), 4x4 frags of mfma_f32_16x16x32_f16.
// A row-major fp16 [M][K]; B pre-transposed Bt[N][K] fp16 (hi [+ lo if SPLIT]).
// LDS [128 rows][8 slots of 8 fp16], slot stored at slot^(row&7) (same index
// fn on write & read -> self-consistent, conflict-free b128 frag reads).
// EPI: 0 = write gbuf + BN column partials (GEMM1)
//      1 = u/rx gate epilogue (GEMM2, cols 0..2047 of 3072-space)
//      2 = final hy epilogue (GEMM3, cols 2048..3071)

#define BM 128
#define BN 128
#define BK 64

template <int EPI, bool SPLIT>
__global__ __launch_bounds__(256, 3) void gemm16(
    const _Float16* __restrict__ A, const _Float16* __restrict__ Bh,
    const _Float16* __restrict__ Bl, float* __restrict__ gbuf,
    const float* __restrict__ scale, const float* __restrict__ shift,
    const _Float16* __restrict__ hxf, _Float16* __restrict__ ubuf,
    _Float16* __restrict__ rxbuf, float* __restrict__ out,
    float* __restrict__ psum, float* __restrict__ psq, int K) {
  constexpr int TE = BM * BK;                  // 8192 fp16 = 16 KiB
  __shared__ _Float16 lds[(SPLIT ? 3 : 2) * TE];

  const int tid  = threadIdx.x;
  const int lane = tid & 63;
  const int wid  = tid >> 6;

  // XCD-aware bijective remap: each XCD owns a column panel (gridDim.x % 8 == 0)
  int flat = blockIdx.y * gridDim.x + blockIdx.x;
  int cpx  = gridDim.x >> 3;                   // col-blocks per XCD
  int xcd  = flat & 7, idx = flat >> 3;
  int bx   = xcd * cpx + idx / gridDim.y;
  int by   = idx % gridDim.y;

  const int brow = by * BM;
  const int bcol = bx * BN;
  const int wrow = (wid >> 1) * 64;
  const int wcol = (wid & 1) * 64;

  f32x4 acc[4][4];
#pragma unroll
  for (int i = 0; i < 4; ++i)
#pragma unroll
    for (int j = 0; j < 4; ++j) acc[i][j] = f32x4{0.f, 0.f, 0.f, 0.f};

  const int NT = K / BK;
  for (int kt = 0; kt < NT; ++kt) {
    const int k0 = kt * BK;

    // global -> registers (overlaps previous tile's compute)
    half8 rA[4], rBh[4], rBl[4];
#pragma unroll
    for (int i = 0; i < 4; ++i) {
      int c = i * 256 + tid;                   // 1024 16B-chunks per tile
      int row = c >> 3, slot = c & 7;
      size_t ko = (size_t)k0 + slot * 8;
      rA[i]  = *(const half8*)(A  + (size_t)(brow + row) * K + ko);
      rBh[i] = *(const half8*)(Bh + (size_t)(bcol + row) * K + ko);
      if constexpr (SPLIT)
        rBl[i] = *(const half8*)(Bl + (size_t)(bcol + row) * K + ko);
    }

    __syncthreads();                           // prev tile's LDS reads done

    // registers -> LDS (XOR-swizzled slots)
#pragma unroll
    for (int i = 0; i < 4; ++i) {
      int c = i * 256 + tid;
      int row = c >> 3, slot = c & 7;
      int off = row * 64 + ((slot ^ (row & 7)) << 3);
      *(half8*)(lds + off)      = rA[i];
      *(half8*)(lds + TE + off) = rBh[i];
      if constexpr (SPLIT) *(half8*)(lds + 2 * TE + off) = rBl[i];
    }
    __syncthreads();                           // staged data visible

    // compute: two K=32 halves
#pragma unroll
    for (int h = 0; h < 2; ++h) {
      half8 a[4], bh[4], bl[4];
      const int kg = h * 4 + (lane >> 4);      // 16B k-group 0..7
#pragma unroll
      for (int m = 0; m < 4; ++m) {
        int r = wrow + m * 16 + (lane & 15);
        int off = r * 64 + ((kg ^ (r & 7)) << 3);
        a[m] = *(const half8*)(lds + off);
      }
#pragma unroll
      for (int n = 0; n < 4; ++n) {
        int r = wcol + n * 16 + (lane & 15);
        int off = r * 64 + ((kg ^ (r & 7)) << 3);
        bh[n] = *(const half8*)(lds + TE + off);
        if constexpr (SPLIT) bl[n] = *(const half8*)(lds + 2 * TE + off);
      }
#pragma unroll
      for (int m = 0; m < 4; ++m)
#pragma unroll
        for (int n = 0; n < 4; ++n) {
          acc[m][n] = __builtin_amdgcn_mfma_f32_16x16x32_f16(
              a[m], bh[n], acc[m][n], 0, 0, 0);
          if constexpr (SPLIT)
            acc[m][n] = __builtin_amdgcn_mfma_f32_16x16x32_f16(
                a[m], bl[n], acc[m][n], 0, 0, 0);
        }
    }
  }

  // ---- epilogues.  D(row,col): col = lane&15, row = (lane>>4)*4 + j.
  if constexpr (EPI == 0) {
    float s[4] = {0, 0, 0, 0}, q[4] = {0, 0, 0, 0};
#pragma unroll
    for (int m = 0; m < 4; ++m) {
      int row = brow + wrow + m * 16 + (lane >> 4) * 4;
#pragma unroll
      for (int n = 0; n < 4; ++n) {
        int gcol = bcol + wcol + n * 16 + (lane & 15);
#pragma unroll
        for (int j = 0; j < 4; ++j) {
          float v = acc[m][n][j];
          gbuf[(size_t)(row + j) * 3072 + gcol] = v;
          s[n] += v;
          q[n] += v * v;
        }
      }
    }
    // reduce over the 4 lane-groups (rows of this wave's 64-row span)
#pragma unroll
    for (int n = 0; n < 4; ++n) {
      float sv = s[n], qv = q[n];
      sv += __shfl_xor(sv, 16); sv += __shfl_xor(sv, 32);
      qv += __shfl_xor(qv, 16); qv += __shfl_xor(qv, 32);
      if (lane < 16) {
        int prow = by * 2 + (wid >> 1);        // 64 partial rows total
        int pcol = bcol + wcol + n * 16 + lane;
        psum[(size_t)prow * 3072 + pcol] = sv;
        psq [(size_t)prow * 3072 + pcol] = qv;
      }
    }
  } else if constexpr (EPI == 1) {
#pragma unroll
    for (int m = 0; m < 4; ++m) {
      int row0 = brow + wrow + m * 16 + (lane >> 4) * 4;
#pragma unroll
      for (int n = 0; n < 4; ++n) {
        int gcol = bcol + wcol + n * 16 + (lane & 15);   // 0..2047
        float sc = scale[gcol], sf = shift[gcol];
#pragma unroll
        for (int j = 0; j < 4; ++j) {
          int row = row0 + j;
          float pre = gbuf[(size_t)row * 3072 + gcol] * sc + sf + acc[m][n][j];
          if (gcol < 1024) {                   // u gate (uniform per block)
            ubuf[(size_t)row * 1024 + gcol] = (_Float16)sigm(pre);
          } else {                             // r gate -> rx = r * hx
            int hc = gcol - 1024;
            float r = sigm(pre);
            rxbuf[(size_t)row * 1024 + hc] =
                (_Float16)(r * (float)hxf[(size_t)row * 1024 + hc]);
          }
        }
      }
    }
  } else {  // EPI == 2: hy = hx + u*(c - hx)
#pragma unroll
    for (int m = 0; m < 4; ++m) {
      int row0 = brow + wrow + m * 16 + (lane >> 4) * 4;
#pragma unroll
      for (int n = 0; n < 4; ++n) {
        int lcol = bcol + wcol + n * 16 + (lane & 15);   // 0..1023
        int gcol = 2048 + lcol;
        float sc = scale[gcol], sf = shift[gcol];
#pragma unroll
        for (int j = 0; j < 4; ++j) {
          int row = row0 + j;
          float t = gbuf[(size_t)row * 3072 + gcol] * sc + sf + acc[m][n][j];
          float c = tanh_sat(t);
          float u = (float)ubuf[(size_t)row * 1024 + lcol];
          float x = (float)hxf[(size_t)row * 1024 + lcol];
          out[(size_t)row * 1024 + lcol] = x + u * (c - x);
        }
      }
    }
  }
}

// --------------------------- BN final ---------------------------------------

__global__ void bn_final(const float* __restrict__ psum, const float* __restrict__ psq,
                         const float* __restrict__ gamma, const float* __restrict__ beta,
                         const float* __restrict__ bias, float* __restrict__ scale,
                         float* __restrict__ shift, int nparts, int Ncols, float invM) {
  int col = blockIdx.x * blockDim.x + threadIdx.x;
  if (col >= Ncols) return;
  float s = 0.f, q = 0.f;
  for (int i = 0; i < nparts; ++i) {
    s += psum[(size_t)i * Ncols + col];
    q += psq [(size_t)i * Ncols + col];
  }
  float m   = s * invM;
  float var = q * invM - m * m;
  float r   = rsqrtf(var + 1e-5f);
  float sc  = r * gamma[col];
  scale[col] = sc;
  shift[col] = beta[col] + bias[col] - m * sc;
}

// ------------------------------ launch ---------------------------------------

extern "C" void kernel_launch(void* const* d_in, const int* in_sizes, int n_in,
                              void* d_out, int out_size, void* d_ws, size_t ws_size,
                              hipStream_t stream) {
  const float* input = (const float*)d_in[0];   // 4096x1024
  const float* hx    = (const float*)d_in[1];   // 4096x1024
  const float* wi    = (const float*)d_in[2];   // 1024x3072
  const float* wh    = (const float*)d_in[3];   // 1024x3072
  const float* bias  = (const float*)d_in[4];   // 3072
  const float* gamma = (const float*)d_in[5];   // 3072
  const float* beta  = (const float*)d_in[6];   // 3072
  float* out = (float*)d_out;

  const int B = 4096, I = 1024, N3 = 3072;

  char* ws = (char*)d_ws;
  float*    gbuf  = (float*)   (ws);               // 48 MiB  [4096][3072] f32
  _Float16* ubuf  = (_Float16*)(ws + 50331648);    // 8 MiB   u gate fp16
  _Float16* Xf16  = (_Float16*)(ws + 58720256);    // 8 MiB   input fp16
  _Float16* Hf16  = (_Float16*)(ws + 67108864);    // 8 MiB   hx fp16
  _Float16* RXf16 = (_Float16*)(ws + 75497472);    // 8 MiB   rx fp16
  _Float16* WiTh  = (_Float16*)(ws + 83886080);    // 6 MiB   wi^T fp16
  _Float16* WhTh  = (_Float16*)(ws + 90177536);    // 6 MiB   wh^T hi
  _Float16* WhTl  = (_Float16*)(ws + 96468992);    // 6 MiB   wh^T lo
  float*    psum  = (float*)   (ws + 102760448);   // 768 KiB [64][3072]
  float*    psq   = (float*)   (ws + 103546880);   // 768 KiB
  float*    scale = (float*)   (ws + 104333312);   // 12 KiB
  float*    shift = (float*)   (ws + 104345600);   // 12 KiB

  // ---- prep
  convert16<<<4096, 256, 0, stream>>>(input, Xf16, B * I / 4);
  convert16<<<4096, 256, 0, stream>>>(hx, Hf16, B * I / 4);
  transpose16<<<dim3(96, 32), 256, 0, stream>>>(wi, WiTh, nullptr, I, N3);
  transpose16<<<dim3(96, 32), 256, 0, stream>>>(wh, WhTh, WhTl, I, N3);

  // ---- GEMM1 (1-pass): g = input @ wi  -> gbuf + BN partials
  gemm16<0, false><<<dim3(24, 32), 256, 0, stream>>>(
      Xf16, WiTh, nullptr, gbuf, nullptr, nullptr, nullptr, nullptr, nullptr,
      nullptr, psum, psq, I);

  // ---- BN fold
  bn_final<<<12, 256, 0, stream>>>(psum, psq, gamma, beta, bias,
                                   scale, shift, 64, N3, 1.f / (float)B);

  // ---- GEMM2 (2-pass): hx @ wh[:, :2048] -> u (fp16) and rx (fp16)
  gemm16<1, true><<<dim3(16, 32), 256, 0, stream>>>(
      Hf16, WhTh, WhTl, gbuf, scale, shift, Hf16, ubuf, RXf16,
      nullptr, nullptr, nullptr, I);

  // ---- GEMM3 (2-pass): rx @ wh[:, 2048:] -> hy
  gemm16<2, true><<<dim3(8, 32), 256, 0, stream>>>(
      RXf16, WhTh + (size_t)2048 * 1024, WhTl + (size_t)2048 * 1024, gbuf,
      scale, shift, Hf16, ubuf, nullptr, out, nullptr, nullptr, I);
}

// Round 5
// 160.883 us; speedup vs baseline: 1.5868x; 1.0978x over previous
//
#include <hip/hip_runtime.h>
#include <cstdint>

// ---------------------------------------------------------------------------
// GRUCell w/ BatchNorm on input projection.  B=4096, I=H=1024, 3H=3072.
// Reference:  c = tanh(c_bn + (r * hx) @ c_h)  (Python left-assoc * then @).
// fp16 scheme (mfma_f32_16x16x32_f16, fp32 accum):
//   GEMM1: g  = input @ wi          1-pass (BN divides error by sigma~32)
//   GEMM2: gh = hx @ wh[:, :2H]     2-pass (B split hi+lo fp16)
//   GEMM3: ch = rx @ wh[:, 2H:]     2-pass, BN-tile=64 for 2 blocks/CU
// Pipelined staging: issue load(kt+1) BEFORE compute(kt) so HBM/L2 latency
// hides under MFMA (round-4 exposed it fully -> MfmaUtil 18%).
// Fused epilogues: GEMM1 -> g fp16 + BN partials; GEMM2 -> u + rx; GEMM3 -> hy.
// ---------------------------------------------------------------------------

typedef float    f4    __attribute__((ext_vector_type(4)));
typedef _Float16 half4 __attribute__((ext_vector_type(4)));
typedef _Float16 half8 __attribute__((ext_vector_type(8)));
typedef float    f32x4 __attribute__((ext_vector_type(4)));

__device__ __forceinline__ float sigm(float x) { return 1.f / (1.f + __expf(-x)); }
__device__ __forceinline__ float tanh_sat(float t) {
  return 1.f - 2.f / (__expf(2.f * t) + 1.f);   // saturates correctly for big t
}

// --------------------------- prep kernels ----------------------------------

// two f32 arrays -> fp16, vectorized x4, single dispatch
__global__ void convert2(const float* __restrict__ a, const float* __restrict__ b,
                         _Float16* __restrict__ da, _Float16* __restrict__ db,
                         int n4each) {
  int i = blockIdx.x * blockDim.x + threadIdx.x;
  const float* s;
  _Float16* d;
  if (i < n4each) { s = a; d = da; }
  else            { s = b; d = db; i -= n4each; }
  f4 v = ((const f4*)s)[i];
  half4 h;
#pragma unroll
  for (int j = 0; j < 4; ++j) h[j] = (_Float16)v[j];
  ((half4*)d)[i] = h;
}

// wi -> WiT (no split), wh -> WhTh/WhTl (split), one dispatch (blockIdx.z)
__global__ void transpose2(const float* __restrict__ wi, const float* __restrict__ wh,
                           _Float16* __restrict__ WiT, _Float16* __restrict__ WhTh,
                           _Float16* __restrict__ WhTl, int K, int N) {
  __shared__ float sh[32][33];
  const bool split = blockIdx.z != 0;
  const float* W = split ? wh : wi;
  int n0 = blockIdx.x * 32, k0 = blockIdx.y * 32;
  int tx = threadIdx.x & 31, ty = threadIdx.x >> 5;  // ty 0..7
#pragma unroll
  for (int i = 0; i < 4; ++i) {
    int k = ty + i * 8;
    sh[k][tx] = W[(size_t)(k0 + k) * N + n0 + tx];
  }
  __syncthreads();
#pragma unroll
  for (int i = 0; i < 4; ++i) {
    int nn = ty + i * 8;
    float v = sh[tx][nn];                      // = W[k0+tx][n0+nn]
    size_t o = (size_t)(n0 + nn) * K + k0 + tx;
    _Float16 h = (_Float16)v;
    if (!split) {
      WiT[o] = h;
    } else {
      WhTh[o] = h;
      WhTl[o] = (_Float16)(v - (float)h);
    }
  }
}

// ------------------------------- GEMM ---------------------------------------
// BM=128 x BNt tile, BK=64, 4 waves (2x2), wave = 64 x (BNt/2), frags of
// mfma_f32_16x16x32_f16.  A row-major fp16 [M][1024]; B pre-transposed
// Bt[N][1024] fp16 (hi [+lo if SPLIT]).  LDS [rows][8 slots of 8 fp16],
// slot stored at slot^(row&7) (same fn write & read -> conflict-free b128).
// K-loop pipelined: store(kt); barrier; load(kt+1); compute(kt).

#define BM 128
#define BK 64

template <int EPI, bool SPLIT, int BNt>
__global__ __launch_bounds__(256, 3) void gemm16(
    const _Float16* __restrict__ A, const _Float16* __restrict__ Bh,
    const _Float16* __restrict__ Bl, _Float16* __restrict__ g16,
    const float* __restrict__ scale, const float* __restrict__ shift,
    const _Float16* __restrict__ hxf, _Float16* __restrict__ ubuf,
    _Float16* __restrict__ rxbuf, float* __restrict__ out,
    float* __restrict__ psum, float* __restrict__ psq) {
  constexpr int K  = 1024;
  constexpr int NT = K / BK;                    // 16
  constexpr int TA = BM * BK;                   // 8192 fp16
  constexpr int TB = BNt * BK;                  // 8192 or 4096
  constexpr int WCOLS = BNt / 32;               // n-frags per wave: 4 or 2
  constexpr int ACH = TA / 2048;                // 4 chunks/thread for A
  constexpr int BCH = TB / 2048;                // 4 or 2 for B
  __shared__ _Float16 lds[TA + TB * (SPLIT ? 2 : 1)];

  const int tid  = threadIdx.x;
  const int lane = tid & 63;
  const int wid  = tid >> 6;

  // XCD-aware bijective remap (gridDim.x % 8 == 0): XCD owns a column panel
  int flat = blockIdx.y * gridDim.x + blockIdx.x;
  int cpx  = gridDim.x >> 3;
  int xcd  = flat & 7, idx = flat >> 3;
  int bx   = xcd * cpx + idx / gridDim.y;
  int by   = idx % gridDim.y;

  const int brow = by * BM;
  const int bcol = bx * BNt;
  const int wrow = (wid >> 1) * 64;
  const int wcol = (wid & 1) * (BNt / 2);

  half8 rA[ACH], rBh[BCH], rBl[BCH];

  auto load_tile = [&](int kt) {
    const int k0 = kt * BK;
#pragma unroll
    for (int i = 0; i < ACH; ++i) {
      int c = i * 256 + tid, row = c >> 3, slot = c & 7;
      rA[i] = *(const half8*)(A + (size_t)(brow + row) * K + k0 + slot * 8);
    }
#pragma unroll
    for (int i = 0; i < BCH; ++i) {
      int c = i * 256 + tid, row = c >> 3, slot = c & 7;
      size_t o = (size_t)(bcol + row) * K + k0 + slot * 8;
      rBh[i] = *(const half8*)(Bh + o);
      if constexpr (SPLIT) rBl[i] = *(const half8*)(Bl + o);
    }
  };
  auto store_tile = [&]() {
#pragma unroll
    for (int i = 0; i < ACH; ++i) {
      int c = i * 256 + tid, row = c >> 3, slot = c & 7;
      int off = row * 64 + ((slot ^ (row & 7)) << 3);
      *(half8*)(lds + off) = rA[i];
    }
#pragma unroll
    for (int i = 0; i < BCH; ++i) {
      int c = i * 256 + tid, row = c >> 3, slot = c & 7;
      int off = row * 64 + ((slot ^ (row & 7)) << 3);
      *(half8*)(lds + TA + off) = rBh[i];
      if constexpr (SPLIT) *(half8*)(lds + TA + TB + off) = rBl[i];
    }
  };

  f32x4 acc[4][WCOLS];
#pragma unroll
  for (int i = 0; i < 4; ++i)
#pragma unroll
    for (int j = 0; j < WCOLS; ++j) acc[i][j] = f32x4{0.f, 0.f, 0.f, 0.f};

  load_tile(0);
  for (int kt = 0; kt < NT; ++kt) {
    __syncthreads();                  // prev tile's LDS reads done
    store_tile();
    __syncthreads();                  // staged data visible
    if (kt + 1 < NT) load_tile(kt + 1);   // latency hides under compute below

#pragma unroll
    for (int h = 0; h < 2; ++h) {
      half8 a[4], bh[WCOLS], bl[WCOLS];
      const int kg = h * 4 + (lane >> 4);
#pragma unroll
      for (int m = 0; m < 4; ++m) {
        int r = wrow + m * 16 + (lane & 15);
        a[m] = *(const half8*)(lds + r * 64 + ((kg ^ (r & 7)) << 3));
      }
#pragma unroll
      for (int n = 0; n < WCOLS; ++n) {
        int r = wcol + n * 16 + (lane & 15);
        int off = TA + r * 64 + ((kg ^ (r & 7)) << 3);
        bh[n] = *(const half8*)(lds + off);
        if constexpr (SPLIT) bl[n] = *(const half8*)(lds + TB + off);
      }
#pragma unroll
      for (int m = 0; m < 4; ++m)
#pragma unroll
        for (int n = 0; n < WCOLS; ++n) {
          acc[m][n] = __builtin_amdgcn_mfma_f32_16x16x32_f16(
              a[m], bh[n], acc[m][n], 0, 0, 0);
          if constexpr (SPLIT)
            acc[m][n] = __builtin_amdgcn_mfma_f32_16x16x32_f16(
                a[m], bl[n], acc[m][n], 0, 0, 0);
        }
    }
  }

  // ---- epilogues.  D(row,col): col = lane&15, row = (lane>>4)*4 + j.
  if constexpr (EPI == 0) {           // g (fp16) + BN column partial sums
    float s[4] = {0, 0, 0, 0}, q[4] = {0, 0, 0, 0};
#pragma unroll
    for (int m = 0; m < 4; ++m) {
      int row = brow + wrow + m * 16 + (lane >> 4) * 4;
#pragma unroll
      for (int n = 0; n < 4; ++n) {
        int gcol = bcol + wcol + n * 16 + (lane & 15);
#pragma unroll
        for (int j = 0; j < 4; ++j) {
          float v = acc[m][n][j];
          g16[(size_t)(row + j) * 3072 + gcol] = (_Float16)v;
          s[n] += v;
          q[n] += v * v;
        }
      }
    }
#pragma unroll
    for (int n = 0; n < 4; ++n) {
      float sv = s[n], qv = q[n];
      sv += __shfl_xor(sv, 16); sv += __shfl_xor(sv, 32);
      qv += __shfl_xor(qv, 16); qv += __shfl_xor(qv, 32);
      if (lane < 16) {
        int prow = by * 2 + (wid >> 1);          // 64 partial rows
        int pcol = bcol + wcol + n * 16 + lane;
        psum[(size_t)prow * 3072 + pcol] = sv;
        psq [(size_t)prow * 3072 + pcol] = qv;
      }
    }
  } else if constexpr (EPI == 1) {    // u gate (fp16) + rx = r*hx (fp16)
#pragma unroll
    for (int m = 0; m < 4; ++m) {
      int row0 = brow + wrow + m * 16 + (lane >> 4) * 4;
#pragma unroll
      for (int n = 0; n < 4; ++n) {
        int gcol = bcol + wcol + n * 16 + (lane & 15);   // 0..2047
        float sc = scale[gcol], sf = shift[gcol];
#pragma unroll
        for (int j = 0; j < 4; ++j) {
          int row = row0 + j;
          float pre = (float)g16[(size_t)row * 3072 + gcol] * sc + sf
                      + acc[m][n][j];
          if (gcol < 1024) {
            ubuf[(size_t)row * 1024 + gcol] = (_Float16)sigm(pre);
          } else {
            int hc = gcol - 1024;
            float r = sigm(pre);
            rxbuf[(size_t)row * 1024 + hc] =
                (_Float16)(r * (float)hxf[(size_t)row * 1024 + hc]);
          }
        }
      }
    }
  } else {                            // EPI == 2: hy = hx + u*(c - hx)
#pragma unroll
    for (int m = 0; m < 4; ++m) {
      int row0 = brow + wrow + m * 16 + (lane >> 4) * 4;
#pragma unroll
      for (int n = 0; n < WCOLS; ++n) {
        int lcol = bcol + wcol + n * 16 + (lane & 15);   // 0..1023
        int gcol = 2048 + lcol;
        float sc = scale[gcol], sf = shift[gcol];
#pragma unroll
        for (int j = 0; j < 4; ++j) {
          int row = row0 + j;
          float t = (float)g16[(size_t)row * 3072 + gcol] * sc + sf
                    + acc[m][n][j];
          float c = tanh_sat(t);
          float u = (float)ubuf[(size_t)row * 1024 + lcol];
          float x = (float)hxf[(size_t)row * 1024 + lcol];
          out[(size_t)row * 1024 + lcol] = x + u * (c - x);
        }
      }
    }
  }
}

// --------------------------- BN final ---------------------------------------

__global__ void bn_final(const float* __restrict__ psum, const float* __restrict__ psq,
                         const float* __restrict__ gamma, const float* __restrict__ beta,
                         const float* __restrict__ bias, float* __restrict__ scale,
                         float* __restrict__ shift, int nparts, int Ncols, float invM) {
  int col = blockIdx.x * blockDim.x + threadIdx.x;
  if (col >= Ncols) return;
  float s = 0.f, q = 0.f;
  for (int i = 0; i < nparts; ++i) {
    s += psum[(size_t)i * Ncols + col];
    q += psq [(size_t)i * Ncols + col];
  }
  float m   = s * invM;
  float var = q * invM - m * m;
  float r   = rsqrtf(var + 1e-5f);
  float sc  = r * gamma[col];
  scale[col] = sc;
  shift[col] = beta[col] + bias[col] - m * sc;
}

// ------------------------------ launch ---------------------------------------

extern "C" void kernel_launch(void* const* d_in, const int* in_sizes, int n_in,
                              void* d_out, int out_size, void* d_ws, size_t ws_size,
                              hipStream_t stream) {
  const float* input = (const float*)d_in[0];   // 4096x1024
  const float* hx    = (const float*)d_in[1];   // 4096x1024
  const float* wi    = (const float*)d_in[2];   // 1024x3072
  const float* wh    = (const float*)d_in[3];   // 1024x3072
  const float* bias  = (const float*)d_in[4];   // 3072
  const float* gamma = (const float*)d_in[5];   // 3072
  const float* beta  = (const float*)d_in[6];   // 3072
  float* out = (float*)d_out;

  const int B = 4096, I = 1024, N3 = 3072;

  char* ws = (char*)d_ws;
  _Float16* g16   = (_Float16*)(ws);               // 24 MiB [4096][3072] fp16
  _Float16* ubuf  = (_Float16*)(ws + 25165824);    // 8 MiB
  _Float16* Xf16  = (_Float16*)(ws + 33554432);    // 8 MiB
  _Float16* Hf16  = (_Float16*)(ws + 41943040);    // 8 MiB
  _Float16* RXf16 = (_Float16*)(ws + 50331648);    // 8 MiB
  _Float16* WiT   = (_Float16*)(ws + 58720256);    // 6 MiB
  _Float16* WhTh  = (_Float16*)(ws + 65011712);    // 6 MiB
  _Float16* WhTl  = (_Float16*)(ws + 71303168);    // 6 MiB
  float*    psum  = (float*)   (ws + 77594624);    // 768 KiB [64][3072]
  float*    psq   = (float*)   (ws + 78381056);    // 768 KiB
  float*    scale = (float*)   (ws + 79167488);    // 12 KiB
  float*    shift = (float*)   (ws + 79179776);    // 12 KiB

  // ---- prep (2 dispatches)
  convert2<<<8192, 256, 0, stream>>>(input, hx, Xf16, Hf16, B * I / 4);
  transpose2<<<dim3(96, 32, 2), 256, 0, stream>>>(wi, wh, WiT, WhTh, WhTl, I, N3);

  // ---- GEMM1 (1-pass): g = input @ wi -> g16 + BN partials
  gemm16<0, false, 128><<<dim3(24, 32), 256, 0, stream>>>(
      Xf16, WiT, nullptr, g16, nullptr, nullptr, nullptr, nullptr, nullptr,
      nullptr, psum, psq);

  // ---- BN fold
  bn_final<<<12, 256, 0, stream>>>(psum, psq, gamma, beta, bias,
                                   scale, shift, 64, N3, 1.f / (float)B);

  // ---- GEMM2 (2-pass): hx @ wh[:, :2048] -> u (fp16), rx (fp16)
  gemm16<1, true, 128><<<dim3(16, 32), 256, 0, stream>>>(
      Hf16, WhTh, WhTl, g16, scale, shift, Hf16, ubuf, RXf16,
      nullptr, nullptr, nullptr);

  // ---- GEMM3 (2-pass, BNt=64): rx @ wh[:, 2048:] -> hy
  gemm16<2, true, 64><<<dim3(16, 32), 256, 0, stream>>>(
      RXf16, WhTh + (size_t)2048 * 1024, WhTl + (size_t)2048 * 1024, g16,
      scale, shift, Hf16, ubuf, nullptr, out, nullptr, nullptr);
}